// Round 2
// baseline (286.075 us; speedup 1.0000x reference)
//
#include <hip/hip_runtime.h>
#include <cmath>
#include <cstdint>
#include <cstring>

// ---------------------------------------------------------------------------
// Host-side reproduction of eps = jax.random.normal(jax.random.key(42), (4,4))
// key(42) -> threefry2x32 key pair (0, 42).
//
// JAX >= 0.4.36/0.5.0 defaults jax_threefry_partitionable=True. In that mode
// random_bits(key, 32, shape) gives each element e a 64-bit counter e, split
// (hi, lo) = (e>>32, e&0xffffffff) = (0, e) here, runs one threefry2x32 per
// element, and XOR-folds the two 32-bit outputs: bits[e] = out0 ^ out1.
// (The legacy stream — iota(16) split 8/8, outputs concatenated — was tried in
// round 1 and mismatched: absmax 2.875 with all non-eps logic verified.)
//
// uniform: f32(bits>>9 | 0x3f800000) - 1, scaled to [nextafter(-1,0), 1)
// normal:  sqrt(2) * erfinv(u)
//
// Threefry core hand-verified against Random123 KAT:
//   key (0,0), ctr (0,0) -> (0x6b200159, 0x99ba4efe)  [20 rounds]
// ---------------------------------------------------------------------------

static inline uint32_t rotl32(uint32_t v, int r) { return (v << r) | (v >> (32 - r)); }

static void threefry2x32_42(uint32_t x0, uint32_t x1, uint32_t& o0, uint32_t& o1) {
    const uint32_t k0 = 0u, k1 = 42u;
    const uint32_t ks[3] = { k0, k1, k0 ^ k1 ^ 0x1BD11BDAu };
    static const int R[8] = { 13, 15, 26, 6, 17, 29, 16, 24 };
    x0 += ks[0];
    x1 += ks[1];
    for (int g = 1; g <= 5; ++g) {
        const int* rr = &R[((g - 1) & 1) * 4];
        for (int j = 0; j < 4; ++j) {
            x0 += x1;
            x1 = rotl32(x1, rr[j]);
            x1 ^= x0;
        }
        x0 += ks[g % 3];
        x1 += ks[(g + 1) % 3] + (uint32_t)g;
    }
    o0 = x0;
    o1 = x1;
}

static double erfinv_d(double x) {
    // Giles single-precision approximation as a seed, then Newton in double.
    float xf = (float)x;
    float w = -logf((1.0f - xf) * (1.0f + xf));
    float p;
    if (w < 5.0f) {
        w -= 2.5f;
        p = 2.81022636e-08f;
        p = fmaf(p, w, 3.43273939e-07f);
        p = fmaf(p, w, -3.5233877e-06f);
        p = fmaf(p, w, -4.39150654e-06f);
        p = fmaf(p, w, 0.00021858087f);
        p = fmaf(p, w, -0.00125372503f);
        p = fmaf(p, w, -0.00417768164f);
        p = fmaf(p, w, 0.246640727f);
        p = fmaf(p, w, 1.50140941f);
    } else {
        w = sqrtf(w) - 3.0f;
        p = -0.000200214257f;
        p = fmaf(p, w, 0.000100950558f);
        p = fmaf(p, w, 0.00134934322f);
        p = fmaf(p, w, -0.00367342844f);
        p = fmaf(p, w, 0.00573950773f);
        p = fmaf(p, w, -0.0076224613f);
        p = fmaf(p, w, 0.00943887047f);
        p = fmaf(p, w, 1.00167406f);
        p = fmaf(p, w, 2.83297682f);
    }
    double y = (double)(p * xf);
    const double c = 1.1283791670955126; // 2/sqrt(pi)
    for (int it = 0; it < 3; ++it) {
        double err = erf(y) - x;
        y -= err / (c * exp(-y * y));
    }
    return y;
}

struct EpsT { float e[16]; };

static void compute_eps(float* e) {
    const float lo = -0.99999994f; // nextafterf(-1, 0)
    for (int i = 0; i < 16; ++i) {
        uint32_t a, b;
        // partitionable counter: (hi, lo) = (0, linear_index)
        threefry2x32_42(0u, (uint32_t)i, a, b);
        uint32_t bits = a ^ b;   // 32-bit XOR fold of the 2x32 output
        uint32_t fb = (bits >> 9) | 0x3f800000u;
        float f;
        memcpy(&f, &fb, 4);
        float u = f - 1.0f;        // [0, 1)
        float v = u * 2.0f + lo;   // (1 - lo) rounds to exactly 2.0f in f32
        if (v < lo) v = lo;
        e[i] = (float)(sqrt(2.0) * erfinv_d((double)v));
    }
}

// ---------------------------------------------------------------------------
// Kernel: one thread per batch row. Fully unrolled 16->32->32->4 net, x4
// columns. Weights accessed with wave-uniform constant offsets -> s_load.
// masked input: z[b,l,f] * mask[f, i]  (broadcast over LAST dim, per ref).
// cond[i] = any(mask[:, i]); if false, column i passes z through exactly.
// ---------------------------------------------------------------------------

__global__ __launch_bounds__(256) void scm_kernel(
    const float* __restrict__ z,
    const float* __restrict__ W1, const float* __restrict__ b1,
    const float* __restrict__ W2, const float* __restrict__ b2,
    const float* __restrict__ W3, const float* __restrict__ b3,
    const int* __restrict__ mask,
    float* __restrict__ out, EpsT ep, int B)
{
    const int b = blockIdx.x * 256 + threadIdx.x;
    if (b >= B) return;
    const size_t base = (size_t)b * 16;

    float zr[16];
    const float4* zp = reinterpret_cast<const float4*>(z + base);
    #pragma unroll
    for (int q = 0; q < 4; ++q) {
        float4 v = zp[q];
        zr[q * 4 + 0] = v.x;
        zr[q * 4 + 1] = v.y;
        zr[q * 4 + 2] = v.z;
        zr[q * 4 + 3] = v.w;
    }

    int mk[16];
    #pragma unroll
    for (int t = 0; t < 16; ++t) mk[t] = mask[t];   // uniform -> SGPR

    float ov[16];
    #pragma unroll
    for (int i = 0; i < 4; ++i) {
        const int cond = mk[0 + i] | mk[4 + i] | mk[8 + i] | mk[12 + i];
        if (cond) {
            float h1[32];
            #pragma unroll
            for (int h = 0; h < 32; ++h) h1[h] = b1[h];
            #pragma unroll
            for (int k = 0; k < 16; ++k) {
                const float zm = mk[(k & 3) * 4 + i] ? zr[k] : 0.0f;
                #pragma unroll
                for (int h = 0; h < 32; ++h)
                    h1[h] = fmaf(zm, W1[k * 32 + h], h1[h]);
            }
            #pragma unroll
            for (int h = 0; h < 32; ++h) h1[h] = h1[h] > 0.0f ? h1[h] : 0.0f;

            float h2[32];
            #pragma unroll
            for (int m = 0; m < 32; ++m) h2[m] = b2[m];
            #pragma unroll
            for (int k = 0; k < 32; ++k) {
                const float a = h1[k];
                #pragma unroll
                for (int m = 0; m < 32; ++m)
                    h2[m] = fmaf(a, W2[k * 32 + m], h2[m]);
            }
            #pragma unroll
            for (int m = 0; m < 32; ++m) h2[m] = h2[m] > 0.0f ? h2[m] : 0.0f;

            #pragma unroll
            for (int f = 0; f < 4; ++f) {
                float acc = b3[f] + ep.e[i * 4 + f];
                #pragma unroll
                for (int m = 0; m < 32; ++m)
                    acc = fmaf(h2[m], W3[m * 4 + f], acc);
                ov[i * 4 + f] = acc;
            }
        } else {
            #pragma unroll
            for (int f = 0; f < 4; ++f) ov[i * 4 + f] = zr[i * 4 + f];
        }
    }

    float4* op = reinterpret_cast<float4*>(out + base);
    #pragma unroll
    for (int q = 0; q < 4; ++q)
        op[q] = make_float4(ov[q * 4 + 0], ov[q * 4 + 1], ov[q * 4 + 2], ov[q * 4 + 3]);
}

extern "C" void kernel_launch(void* const* d_in, const int* in_sizes, int n_in,
                              void* d_out, int out_size, void* d_ws, size_t ws_size,
                              hipStream_t stream) {
    const float* z  = (const float*)d_in[0];
    // d_in[1] = z_int (dead code in reference)
    const float* W1 = (const float*)d_in[2];
    const float* b1 = (const float*)d_in[3];
    const float* W2 = (const float*)d_in[4];
    const float* b2 = (const float*)d_in[5];
    const float* W3 = (const float*)d_in[6];
    const float* b3 = (const float*)d_in[7];
    const int* mask = (const int*)d_in[8];
    // d_in[9] = I (dead code in reference)
    float* out = (float*)d_out;

    const int B = in_sizes[0] / 16;

    EpsT ep;
    compute_eps(ep.e);   // pure host math, deterministic, capture-safe

    dim3 grid((B + 255) / 256), block(256);
    hipLaunchKernelGGL(scm_kernel, grid, block, 0, stream,
                       z, W1, b1, W2, b2, W3, b3, mask, out, ep, B);
}